// Round 8
// baseline (1539.674 us; speedup 1.0000x reference)
//
#include <hip/hip_runtime.h>
#include <hip/hip_bf16.h>
#include <math.h>

// ---------------------------------------------------------------------------
// GIN + JumpingKnowledge(cat) + mean-pool + 2-layer head, eval mode.
// R8: MLP restructured to cap live registers at ~64 floats (R7 showed the
//     compiler scratch-spills zv[64]+out2[64] no matter the VGPR budget):
//       GEMM1 m-outer streaming (z consumed as loaded, W1 rows contiguous),
//       t[64] live; relu/bn1 in place; GEMM2 j-outer streaming vs W2T rows,
//       bn2+pack+store immediately. W2 transposed once (W1 transpose dropped).
//     layer0 same pattern.
// Everything else unchanged from R7 (binned CSC, bf16 h, R5 agg).
// ---------------------------------------------------------------------------

typedef unsigned int uint;
typedef unsigned short ushort;

#define ABITS 14  // bucket = dst >> 14 (16384 nodes/bucket, ~1MB col window)

__device__ __forceinline__ float bf_lo(uint w) { return __uint_as_float(w << 16); }
__device__ __forceinline__ float bf_hi(uint w) { return __uint_as_float(w & 0xffff0000u); }

__device__ __forceinline__ uint pack_bf16(float a, float b) {
  __hip_bfloat16 ha = __float2bfloat16(a);
  __hip_bfloat16 hb = __float2bfloat16(b);
  ushort ua = *(ushort*)&ha, ub = *(ushort*)&hb;
  return (uint)ua | ((uint)ub << 16);
}

__global__ void count_deg_kernel(const int* __restrict__ dst, int* __restrict__ deg, int E) {
  int t = blockIdx.x * blockDim.x + threadIdx.x;
  if (t < E) atomicAdd(&deg[dst[t]], 1);
}

// ---- multi-block exclusive scan: deg[N] -> rp[N+1] (+ cursor copy) --------
__global__ void scan_blocksums(const int* __restrict__ deg, int* __restrict__ bsum, int N) {
  __shared__ int red[256];
  int i = blockIdx.x * 256 + threadIdx.x;
  red[threadIdx.x] = (i < N) ? deg[i] : 0;
  __syncthreads();
  for (int off = 128; off > 0; off >>= 1) {
    if (threadIdx.x < off) red[threadIdx.x] += red[threadIdx.x + off];
    __syncthreads();
  }
  if (threadIdx.x == 0) bsum[blockIdx.x] = red[0];
}

__global__ void scan_bsum(const int* __restrict__ bsum, int* __restrict__ boff,
                          int* __restrict__ rp_last, int B) {
  __shared__ int tmp[1024];
  int t = threadIdx.x;
  int v = (t < B) ? bsum[t] : 0;
  tmp[t] = v;
  __syncthreads();
  for (int off = 1; off < 1024; off <<= 1) {
    int u = (t >= off) ? tmp[t - off] : 0;
    __syncthreads();
    tmp[t] += u;
    __syncthreads();
  }
  if (t < B) boff[t] = tmp[t] - v;
  if (t == 1023) *rp_last = tmp[1023];
}

__global__ void scan_final(const int* __restrict__ deg, const int* __restrict__ boff,
                           int* __restrict__ rp, int* __restrict__ cursor, int N) {
  __shared__ int tmp[256];
  int i = blockIdx.x * 256 + threadIdx.x;
  int v = (i < N) ? deg[i] : 0;
  tmp[threadIdx.x] = v;
  __syncthreads();
  for (int off = 1; off < 256; off <<= 1) {
    int u = (threadIdx.x >= off) ? tmp[threadIdx.x - off] : 0;
    __syncthreads();
    tmp[threadIdx.x] += u;
    __syncthreads();
  }
  if (i < N) {
    int ex = boff[blockIdx.x] + tmp[threadIdx.x] - v;
    rp[i] = ex;
    cursor[i] = ex;
  }
}

// bucket arena cursors: bc[b] = rp[b<<ABITS] (arena ranges == col ranges)
__global__ void init_buckets_kernel(const int* __restrict__ rp, int* __restrict__ bc,
                                    int N, int P) {
  int b = threadIdx.x;
  if (b < P) {
    int lo = b << ABITS;
    if (lo > N) lo = N;
    bc[b] = rp[lo];
  }
}

// Phase A: partition edges into dst-range buckets. 1024 thr x 4 edges/block.
__global__ __launch_bounds__(1024) void bin_edges_kernel(
    const int* __restrict__ src, const int* __restrict__ dst, int* __restrict__ bc,
    int* __restrict__ arena_src, int* __restrict__ arena_dst, int E) {
  __shared__ int cnt[32], base[32];
  for (long chunk = (long)blockIdx.x * 4096; chunk < E; chunk += (long)gridDim.x * 4096) {
    if (threadIdx.x < 32) cnt[threadIdx.x] = 0;
    __syncthreads();
    int s[4], d[4], b[4], r[4];
#pragma unroll
    for (int u = 0; u < 4; ++u) {
      long e = chunk + threadIdx.x + u * 1024;
      if (e < E) {
        s[u] = src[e];
        d[u] = dst[e];
        b[u] = d[u] >> ABITS;
        r[u] = atomicAdd(&cnt[b[u]], 1);
      }
    }
    __syncthreads();
    if (threadIdx.x < 32) base[threadIdx.x] = cnt[threadIdx.x] ? atomicAdd(&bc[threadIdx.x], cnt[threadIdx.x]) : 0;
    __syncthreads();
#pragma unroll
    for (int u = 0; u < 4; ++u) {
      long e = chunk + threadIdx.x + u * 1024;
      if (e < E) {
        int pos = base[b[u]] + r[u];
        arena_src[pos] = s[u];
        arena_dst[pos] = d[u];
      }
    }
    __syncthreads();
  }
}

// Phase B: scatter one bucket; col writes confined to a ~1MB L2-resident window.
__global__ void scatter_bucket_kernel(const int* __restrict__ arena_src,
                                      const int* __restrict__ arena_dst,
                                      const int* __restrict__ rp, int* __restrict__ cursor,
                                      int* __restrict__ col, int lo_node, int hi_node) {
  int start = rp[lo_node], end = rp[hi_node];
  for (int i = start + (int)(blockIdx.x * blockDim.x + threadIdx.x); i < end;
       i += (int)(gridDim.x * blockDim.x)) {
    int s = arena_src[i], d = arena_dst[i];
    int pos = atomicAdd(&cursor[d], 1);
    col[pos] = s;
  }
}

// graph start offsets from sorted batch: gs[g] = first node of graph g, gs[G]=N.
__global__ void graph_bounds_kernel(const int* __restrict__ batch, int* __restrict__ gs,
                                    int N, int G) {
  int n = blockIdx.x * 256 + threadIdx.x;
  if (n >= N) return;
  int b = batch[n];
  int bp = (n == 0) ? -1 : batch[n - 1];
  for (int g = bp + 1; g <= b; ++g) gs[g] = n;
  if (n == N - 1)
    for (int g = b + 1; g <= G; ++g) gs[g] = N;
}

// W2 [8][64][64] -> W2T [8][64][64] with W2T[l][j][k] = W2[l][k][j]
// (row j of W2T = output column j of W2: contiguous for j-outer GEMM2)
__global__ void transpose_w2_kernel(const float* __restrict__ w2, float* __restrict__ w2t) {
  int l = blockIdx.x;
  for (int idx = threadIdx.x; idx < 4096; idx += blockDim.x) {
    int j = idx >> 6, k = idx & 63;
    w2t[l * 4096 + idx] = w2[l * 4096 + k * 64 + j];
  }
}

// z[n][:] = (1+eps_l)*h[n][:] + sum_e h[col[e]][:]   (h bf16, z fp32)
// 8-lane groups; 4 independent 1KB row-gathers in flight (2 nodes x 2 steps).
__global__ __launch_bounds__(256, 6) void agg_kernel(
    const ushort* __restrict__ hb, const int* __restrict__ rp,
    const int* __restrict__ col, const float* __restrict__ eps,
    int layer, float* __restrict__ z, int N) {
  int lane = threadIdx.x & 63;
  int g = lane >> 3;
  int r = lane & 7;
  int wave = blockIdx.x * (blockDim.x >> 6) + (threadIdx.x >> 6);
  int nwaves = gridDim.x * (blockDim.x >> 6);
  float ep = 1.0f + eps[layer];
  for (int n = wave * 2; n < N; n += nwaves * 2) {
    int n0 = __builtin_amdgcn_readfirstlane(n);
    int n1 = n0 + 1;
    int beg0 = rp[n0];
    int end0 = rp[n0 + 1];
    int end1 = (n1 < N) ? rp[n1 + 1] : end0;
    float a0[8] = {0.f, 0.f, 0.f, 0.f, 0.f, 0.f, 0.f, 0.f};
    float a1[8] = {0.f, 0.f, 0.f, 0.f, 0.f, 0.f, 0.f, 0.f};
    float b0[8] = {0.f, 0.f, 0.f, 0.f, 0.f, 0.f, 0.f, 0.f};
    float b1[8] = {0.f, 0.f, 0.f, 0.f, 0.f, 0.f, 0.f, 0.f};
    int e0 = beg0 + g;
    int e1 = end0 + g;
    while (e0 < end0 || e1 < end1) {
      if (e0 < end0) {
        int s = col[e0];
        uint4 w = ((const uint4*)(hb + (long)s * 64))[r];
        a0[0] += bf_lo(w.x); a0[1] += bf_hi(w.x);
        a0[2] += bf_lo(w.y); a0[3] += bf_hi(w.y);
        a0[4] += bf_lo(w.z); a0[5] += bf_hi(w.z);
        a0[6] += bf_lo(w.w); a0[7] += bf_hi(w.w);
      }
      if (e0 + 8 < end0) {
        int s = col[e0 + 8];
        uint4 w = ((const uint4*)(hb + (long)s * 64))[r];
        a1[0] += bf_lo(w.x); a1[1] += bf_hi(w.x);
        a1[2] += bf_lo(w.y); a1[3] += bf_hi(w.y);
        a1[4] += bf_lo(w.z); a1[5] += bf_hi(w.z);
        a1[6] += bf_lo(w.w); a1[7] += bf_hi(w.w);
      }
      if (e1 < end1) {
        int s = col[e1];
        uint4 w = ((const uint4*)(hb + (long)s * 64))[r];
        b0[0] += bf_lo(w.x); b0[1] += bf_hi(w.x);
        b0[2] += bf_lo(w.y); b0[3] += bf_hi(w.y);
        b0[4] += bf_lo(w.z); b0[5] += bf_hi(w.z);
        b0[6] += bf_lo(w.w); b0[7] += bf_hi(w.w);
      }
      if (e1 + 8 < end1) {
        int s = col[e1 + 8];
        uint4 w = ((const uint4*)(hb + (long)s * 64))[r];
        b1[0] += bf_lo(w.x); b1[1] += bf_hi(w.x);
        b1[2] += bf_lo(w.y); b1[3] += bf_hi(w.y);
        b1[4] += bf_lo(w.z); b1[5] += bf_hi(w.z);
        b1[6] += bf_lo(w.w); b1[7] += bf_hi(w.w);
      }
      e0 += 16; e1 += 16;
    }
#pragma unroll
    for (int j = 0; j < 8; ++j) { a0[j] += a1[j]; b0[j] += b1[j]; }
#pragma unroll
    for (int m = 8; m <= 32; m <<= 1) {
#pragma unroll
      for (int j = 0; j < 8; ++j) {
        a0[j] += __shfl_xor(a0[j], m, 64);
        b0[j] += __shfl_xor(b0[j], m, 64);
      }
    }
    if (g == 0) {
      uint4 hv = ((const uint4*)(hb + (long)n0 * 64))[r];
      float4 z0, z1;
      z0.x = fmaf(ep, bf_lo(hv.x), a0[0]); z0.y = fmaf(ep, bf_hi(hv.x), a0[1]);
      z0.z = fmaf(ep, bf_lo(hv.y), a0[2]); z0.w = fmaf(ep, bf_hi(hv.y), a0[3]);
      z1.x = fmaf(ep, bf_lo(hv.z), a0[4]); z1.y = fmaf(ep, bf_hi(hv.z), a0[5]);
      z1.z = fmaf(ep, bf_lo(hv.w), a0[6]); z1.w = fmaf(ep, bf_hi(hv.w), a0[7]);
      float4* zr = (float4*)(z + (long)n0 * 64 + r * 8);
      zr[0] = z0; zr[1] = z1;
    } else if (g == 1 && n1 < N) {
      uint4 hv = ((const uint4*)(hb + (long)n1 * 64))[r];
      float4 z0, z1;
      z0.x = fmaf(ep, bf_lo(hv.x), b0[0]); z0.y = fmaf(ep, bf_hi(hv.x), b0[1]);
      z0.z = fmaf(ep, bf_lo(hv.y), b0[2]); z0.w = fmaf(ep, bf_hi(hv.y), b0[3]);
      z1.x = fmaf(ep, bf_lo(hv.z), b0[4]); z1.y = fmaf(ep, bf_hi(hv.z), b0[5]);
      z1.z = fmaf(ep, bf_lo(hv.w), b0[6]); z1.w = fmaf(ep, bf_hi(hv.w), b0[7]);
      float4* zr = (float4*)(z + (long)n1 * 64 + r * 8);
      zr[0] = z0; zr[1] = z1;
    }
  }
}

// Fused 64->64->64 MLP + relu/bn twice. One node per lane.
// Streaming form: GEMM1 m-outer (z consumed as loaded; W1 rows contiguous),
// only t[64] live; GEMM2 j-outer vs W2T rows, result stored immediately.
__global__ __launch_bounds__(64, 1) void mlp_kernel(
    const float* __restrict__ z, ushort* __restrict__ hout,
    const float* __restrict__ W1, const float* __restrict__ b1,
    const float* __restrict__ g1, const float* __restrict__ be1,
    const float* __restrict__ m1, const float* __restrict__ v1,
    const float* __restrict__ W2T, const float* __restrict__ b2,
    const float* __restrict__ g2, const float* __restrict__ be2,
    const float* __restrict__ m2, const float* __restrict__ v2, int N) {
  int n = blockIdx.x * blockDim.x + threadIdx.x;
  if (n >= N) return;
  float t[64];
#pragma unroll
  for (int k = 0; k < 64; ++k) t[k] = b1[k];
  const float4* zp = (const float4*)(z + (long)n * 64);
  for (int m4 = 0; m4 < 16; ++m4) {  // 4 input dims per iter
    float4 zm = zp[m4];
    const float* r0 = W1 + (4 * m4 + 0) * 64;
    const float* r1 = W1 + (4 * m4 + 1) * 64;
    const float* r2 = W1 + (4 * m4 + 2) * 64;
    const float* r3 = W1 + (4 * m4 + 3) * 64;
#pragma unroll
    for (int k = 0; k < 64; ++k) {
      float acc = fmaf(zm.x, r0[k], t[k]);
      acc = fmaf(zm.y, r1[k], acc);
      acc = fmaf(zm.z, r2[k], acc);
      t[k] = fmaf(zm.w, r3[k], acc);
    }
  }
#pragma unroll
  for (int k = 0; k < 64; ++k) {
    float u = fmaxf(t[k], 0.f);
    t[k] = fmaf(u - m1[k], g1[k] * rsqrtf(v1[k] + 1e-5f), be1[k]);
  }
  uint4* hp = (uint4*)(hout + (long)n * 64);
  for (int q = 0; q < 8; ++q) {  // 8 outputs per store
    float u[8];
#pragma unroll
    for (int c = 0; c < 8; ++c) {
      int j = 8 * q + c;
      const float* wt = W2T + j * 64;
      float a0 = b2[j], a1 = 0.f, a2 = 0.f, a3 = 0.f;
#pragma unroll
      for (int k4 = 0; k4 < 16; ++k4) {
        a0 = fmaf(t[4 * k4 + 0], wt[4 * k4 + 0], a0);
        a1 = fmaf(t[4 * k4 + 1], wt[4 * k4 + 1], a1);
        a2 = fmaf(t[4 * k4 + 2], wt[4 * k4 + 2], a2);
        a3 = fmaf(t[4 * k4 + 3], wt[4 * k4 + 3], a3);
      }
      float s = fmaxf((a0 + a1) + (a2 + a3), 0.f);
      u[c] = fmaf(s - m2[j], g2[j] * rsqrtf(v2[j] + 1e-5f), be2[j]);
    }
    uint4 w;
    w.x = pack_bf16(u[0], u[1]);
    w.y = pack_bf16(u[2], u[3]);
    w.z = pack_bf16(u[4], u[5]);
    w.w = pack_bf16(u[6], u[7]);
    hp[q] = w;
  }
}

// Layer 0: scalar input (H_in = 1). Streaming form, t[64] live only.
__global__ __launch_bounds__(64, 1) void layer0_kernel(
    const float* __restrict__ x, const int* __restrict__ rp, const int* __restrict__ col,
    const float* __restrict__ eps,
    const float* __restrict__ W1f, const float* __restrict__ b1,
    const float* __restrict__ g1, const float* __restrict__ be1,
    const float* __restrict__ m1, const float* __restrict__ v1,
    const float* __restrict__ W2T, const float* __restrict__ b2,
    const float* __restrict__ g2, const float* __restrict__ be2,
    const float* __restrict__ m2, const float* __restrict__ v2,
    ushort* __restrict__ hout, int N) {
  int n = blockIdx.x * blockDim.x + threadIdx.x;
  if (n >= N) return;
  int beg = rp[n], end = rp[n + 1];
  float agg = 0.f;
  for (int e = beg; e < end; ++e) agg += x[col[e]];
  float z0 = fmaf(1.0f + eps[0], x[n], agg);
  float t[64];
#pragma unroll
  for (int k = 0; k < 64; ++k) {
    float u = fmaxf(fmaf(z0, W1f[k], b1[k]), 0.f);
    t[k] = fmaf(u - m1[k], g1[k] * rsqrtf(v1[k] + 1e-5f), be1[k]);
  }
  uint4* hp = (uint4*)(hout + (long)n * 64);
  for (int q = 0; q < 8; ++q) {
    float u[8];
#pragma unroll
    for (int c = 0; c < 8; ++c) {
      int j = 8 * q + c;
      const float* wt = W2T + j * 64;
      float a0 = b2[j], a1 = 0.f, a2 = 0.f, a3 = 0.f;
#pragma unroll
      for (int k4 = 0; k4 < 16; ++k4) {
        a0 = fmaf(t[4 * k4 + 0], wt[4 * k4 + 0], a0);
        a1 = fmaf(t[4 * k4 + 1], wt[4 * k4 + 1], a1);
        a2 = fmaf(t[4 * k4 + 2], wt[4 * k4 + 2], a2);
        a3 = fmaf(t[4 * k4 + 3], wt[4 * k4 + 3], a3);
      }
      float s = fmaxf((a0 + a1) + (a2 + a3), 0.f);
      u[c] = fmaf(s - m2[j], g2[j] * rsqrtf(v2[j] + 1e-5f), be2[j]);
    }
    uint4 w;
    w.x = pack_bf16(u[0], u[1]);
    w.y = pack_bf16(u[2], u[3]);
    w.z = pack_bf16(u[4], u[5]);
    w.w = pack_bf16(u[6], u[7]);
    hp[q] = w;
  }
}

// block-per-graph mean-sum using precomputed bounds; no atomics.
__global__ void pool_kernel(const ushort* __restrict__ hb, const int* __restrict__ gs,
                            float* __restrict__ pooled, int layer, int G) {
  int g = blockIdx.x;
  int s = gs[g], e = gs[g + 1];
  int w = threadIdx.x >> 6, lane = threadIdx.x & 63;
  float acc = 0.f;
  for (int n = s + w; n < e; n += 4) {
    ushort u = hb[(long)n * 64 + lane];
    acc += __uint_as_float((uint)u << 16);
  }
  __shared__ float red[4][64];
  red[w][lane] = acc;
  __syncthreads();
  if (w == 0)
    pooled[(long)g * 512 + layer * 64 + lane] =
        ((red[0][lane] + red[1][lane]) + (red[2][lane] + red[3][lane]));
}

__global__ __launch_bounds__(64) void final_kernel(
    const float* __restrict__ pooled, const int* __restrict__ gs,
    const float* __restrict__ lin1_w, const float* __restrict__ lin1_b,
    const float* __restrict__ lin2_w, const float* __restrict__ lin2_b,
    float* __restrict__ out, int G) {
  int g = blockIdx.x;
  int j = threadIdx.x;
  float inv = 1.0f / fmaxf((float)(gs[g + 1] - gs[g]), 1.0f);
  __shared__ float p[512];
  for (int t = j; t < 512; t += 64) p[t] = pooled[(long)g * 512 + t] * inv;
  __syncthreads();
  float a0 = lin1_b[j], a1 = 0.f, a2 = 0.f, a3 = 0.f;
  for (int k = 0; k < 512; k += 4) {
    a0 = fmaf(p[k + 0], lin1_w[(k + 0) * 64 + j], a0);
    a1 = fmaf(p[k + 1], lin1_w[(k + 1) * 64 + j], a1);
    a2 = fmaf(p[k + 2], lin1_w[(k + 2) * 64 + j], a2);
    a3 = fmaf(p[k + 3], lin1_w[(k + 3) * 64 + j], a3);
  }
  float hv = fmaxf((a0 + a1) + (a2 + a3), 0.f);
  __shared__ float hb[64];
  hb[j] = hv;
  __syncthreads();
  __shared__ float lg[3];
  if (j < 3) {
    float a = lin2_b[j];
#pragma unroll
    for (int k = 0; k < 64; ++k) a = fmaf(hb[k], lin2_w[k * 3 + j], a);
    lg[j] = a;
  }
  __syncthreads();
  if (j < 3) {
    float mx = fmaxf(fmaxf(lg[0], lg[1]), lg[2]);
    float lse = mx + logf(expf(lg[0] - mx) + expf(lg[1] - mx) + expf(lg[2] - mx));
    out[g * 3 + j] = lg[j] - lse;
  }
}

extern "C" void kernel_launch(void* const* d_in, const int* in_sizes, int n_in,
                              void* d_out, int out_size, void* d_ws, size_t ws_size,
                              hipStream_t stream) {
  const float* x        = (const float*)d_in[0];
  const int*   edge     = (const int*)d_in[1];
  const int*   batch    = (const int*)d_in[2];
  const float* eps      = (const float*)d_in[4];
  const float* W1_first = (const float*)d_in[5];
  const float* W1_rest  = (const float*)d_in[6];
  const float* b1       = (const float*)d_in[7];
  const float* g1       = (const float*)d_in[8];
  const float* be1      = (const float*)d_in[9];
  const float* m1       = (const float*)d_in[10];
  const float* v1       = (const float*)d_in[11];
  const float* W2       = (const float*)d_in[12];
  const float* b2       = (const float*)d_in[13];
  const float* g2       = (const float*)d_in[14];
  const float* be2      = (const float*)d_in[15];
  const float* m2       = (const float*)d_in[16];
  const float* v2       = (const float*)d_in[17];
  const float* lin1_w   = (const float*)d_in[18];
  const float* lin1_b   = (const float*)d_in[19];
  const float* lin2_w   = (const float*)d_in[20];
  const float* lin2_b   = (const float*)d_in[21];

  int N = in_sizes[0];
  int E = in_sizes[1] / 2;
  int G = out_size / 3;
  const int* esrc = edge;
  const int* edst = edge + E;
  int P = (N + (1 << ABITS) - 1) >> ABITS;  // dst-range buckets (N=100k -> 7)
  if (P > 32) P = 32;                        // LDS array bound (N < 512k)

  size_t off = 0;
  auto alloc = [&](size_t bytes) -> char* {
    char* p = (char*)d_ws + off;
    off += (bytes + 255) & ~(size_t)255;
    return p;
  };
  int SB = (N + 255) / 256;  // scan blocks (must be <= 1024)
  int*    deg    = (int*)alloc((size_t)N * 4);
  int*    rp     = (int*)alloc((size_t)(N + 1) * 4);
  int*    cursor = (int*)alloc((size_t)N * 4);
  int*    col    = (int*)alloc((size_t)E * 4);
  int*    bsum   = (int*)alloc((size_t)SB * 4);
  int*    boff   = (int*)alloc((size_t)SB * 4);
  int*    bc     = (int*)alloc((size_t)32 * 4);
  int*    asrc   = (int*)alloc((size_t)E * 4);
  int*    adst   = (int*)alloc((size_t)E * 4);
  int*    gs     = (int*)alloc((size_t)(G + 1) * 4);
  float*  w2t    = (float*)alloc((size_t)8 * 4096 * 4);
  float*  zbuf   = (float*)alloc((size_t)N * 64 * 4);
  ushort* hA     = (ushort*)alloc((size_t)N * 64 * 2);
  ushort* hB     = (ushort*)alloc((size_t)N * 64 * 2);
  float*  pooled = (float*)alloc((size_t)G * 512 * 4);
  (void)ws_size;

  hipMemsetAsync(deg, 0, (size_t)N * 4, stream);
  int eb = (E + 255) / 256;
  count_deg_kernel<<<eb, 256, 0, stream>>>(edst, deg, E);
  scan_blocksums<<<SB, 256, 0, stream>>>(deg, bsum, N);
  scan_bsum<<<1, 1024, 0, stream>>>(bsum, boff, rp + N, SB);
  scan_final<<<SB, 256, 0, stream>>>(deg, boff, rp, cursor, N);

  // two-phase binned CSC build
  init_buckets_kernel<<<1, 64, 0, stream>>>(rp, bc, N, P);
  int ebA = (E + 4095) / 4096;
  bin_edges_kernel<<<ebA, 1024, 0, stream>>>(esrc, edst, bc, asrc, adst, E);
  for (int b = 0; b < P; ++b) {
    int lo = b << ABITS;
    int hi = (b + 1) << ABITS;
    if (hi > N) hi = N;
    if (lo >= N) break;
    scatter_bucket_kernel<<<1024, 256, 0, stream>>>(asrc, adst, rp, cursor, col, lo, hi);
  }

  graph_bounds_kernel<<<SB, 256, 0, stream>>>(batch, gs, N, G);
  transpose_w2_kernel<<<8, 256, 0, stream>>>(W2, w2t);

  int nb64 = (N + 63) / 64;
  layer0_kernel<<<nb64, 64, 0, stream>>>(x, rp, col, eps, W1_first,
      b1, g1, be1, m1, v1, w2t, b2, g2, be2, m2, v2, hA, N);
  pool_kernel<<<G, 256, 0, stream>>>(hA, gs, pooled, 0, G);

  ushort* hin = hA;
  ushort* hout = hB;
  for (int i = 1; i < 8; ++i) {
    agg_kernel<<<2048, 256, 0, stream>>>(hin, rp, col, eps, i, zbuf, N);
    mlp_kernel<<<nb64, 64, 0, stream>>>(zbuf, hout,
        W1_rest + (size_t)(i - 1) * 4096,
        b1 + i * 64, g1 + i * 64, be1 + i * 64, m1 + i * 64, v1 + i * 64,
        w2t + (size_t)i * 4096,
        b2 + i * 64, g2 + i * 64, be2 + i * 64, m2 + i * 64, v2 + i * 64, N);
    pool_kernel<<<G, 256, 0, stream>>>(hout, gs, pooled, i, G);
    ushort* t = hin; hin = hout; hout = t;
  }
  final_kernel<<<G, 64, 0, stream>>>(pooled, gs, lin1_w, lin1_b,
                                     lin2_w, lin2_b, (float*)d_out, G);
}

// Round 9
// 898.134 us; speedup vs baseline: 1.7143x; 1.7143x over previous
//
#include <hip/hip_runtime.h>
#include <hip/hip_bf16.h>
#include <math.h>

// ---------------------------------------------------------------------------
// GIN + JumpingKnowledge(cat) + mean-pool + 2-layer head, eval mode.
// R9: MLP moved to MFMA (bf16 16x16x32) — R6-R8 proved the compiler scratch-
//     spills any float[64] per-lane array (VGPR 60-72, 77-120us). MFMA holds
//     the accumulator in 4x float4 AGPR tiles. Split-bf16 (hi+lo, 3-term
//     MFMA) keeps effective ~16-bit mantissa => absmax unchanged.
//     Weights prepacked once into fragment order. Layer0 = z0 + t0 kernels
//     + the same MFMA kernel in GEMM2-only mode.
// agg/pool/final/CSC unchanged from R7.
// ---------------------------------------------------------------------------

typedef unsigned int uint;
typedef unsigned short ushort;
typedef __attribute__((ext_vector_type(8))) short short8;
typedef __attribute__((ext_vector_type(4))) float floatx4;

#define ABITS 14

__device__ __forceinline__ float bf_lo(uint w) { return __uint_as_float(w << 16); }
__device__ __forceinline__ float bf_hi(uint w) { return __uint_as_float(w & 0xffff0000u); }

__device__ __forceinline__ ushort f2bf(float x) {
  __hip_bfloat16 h = __float2bfloat16(x);
  return *(ushort*)&h;
}
__device__ __forceinline__ float bf2f(ushort u) { return __uint_as_float((uint)u << 16); }

// split two float4s (8 consecutive k-values) into hi/lo bf16 fragments
__device__ __forceinline__ void split8(float4 u0, float4 u1, short8& hi, short8& lo) {
  float v0 = u0.x, v1 = u0.y, v2 = u0.z, v3 = u0.w;
  float v4 = u1.x, v5 = u1.y, v6 = u1.z, v7 = u1.w;
  ushort h0 = f2bf(v0), h1 = f2bf(v1), h2 = f2bf(v2), h3 = f2bf(v3);
  ushort h4 = f2bf(v4), h5 = f2bf(v5), h6 = f2bf(v6), h7 = f2bf(v7);
  hi[0] = (short)h0; hi[1] = (short)h1; hi[2] = (short)h2; hi[3] = (short)h3;
  hi[4] = (short)h4; hi[5] = (short)h5; hi[6] = (short)h6; hi[7] = (short)h7;
  lo[0] = (short)f2bf(v0 - bf2f(h0)); lo[1] = (short)f2bf(v1 - bf2f(h1));
  lo[2] = (short)f2bf(v2 - bf2f(h2)); lo[3] = (short)f2bf(v3 - bf2f(h3));
  lo[4] = (short)f2bf(v4 - bf2f(h4)); lo[5] = (short)f2bf(v5 - bf2f(h5));
  lo[6] = (short)f2bf(v6 - bf2f(h6)); lo[7] = (short)f2bf(v7 - bf2f(h7));
}

__global__ void count_deg_kernel(const int* __restrict__ dst, int* __restrict__ deg, int E) {
  int t = blockIdx.x * blockDim.x + threadIdx.x;
  if (t < E) atomicAdd(&deg[dst[t]], 1);
}

__global__ void scan_blocksums(const int* __restrict__ deg, int* __restrict__ bsum, int N) {
  __shared__ int red[256];
  int i = blockIdx.x * 256 + threadIdx.x;
  red[threadIdx.x] = (i < N) ? deg[i] : 0;
  __syncthreads();
  for (int off = 128; off > 0; off >>= 1) {
    if (threadIdx.x < off) red[threadIdx.x] += red[threadIdx.x + off];
    __syncthreads();
  }
  if (threadIdx.x == 0) bsum[blockIdx.x] = red[0];
}

__global__ void scan_bsum(const int* __restrict__ bsum, int* __restrict__ boff,
                          int* __restrict__ rp_last, int B) {
  __shared__ int tmp[1024];
  int t = threadIdx.x;
  int v = (t < B) ? bsum[t] : 0;
  tmp[t] = v;
  __syncthreads();
  for (int off = 1; off < 1024; off <<= 1) {
    int u = (t >= off) ? tmp[t - off] : 0;
    __syncthreads();
    tmp[t] += u;
    __syncthreads();
  }
  if (t < B) boff[t] = tmp[t] - v;
  if (t == 1023) *rp_last = tmp[1023];
}

__global__ void scan_final(const int* __restrict__ deg, const int* __restrict__ boff,
                           int* __restrict__ rp, int* __restrict__ cursor, int N) {
  __shared__ int tmp[256];
  int i = blockIdx.x * 256 + threadIdx.x;
  int v = (i < N) ? deg[i] : 0;
  tmp[threadIdx.x] = v;
  __syncthreads();
  for (int off = 1; off < 256; off <<= 1) {
    int u = (threadIdx.x >= off) ? tmp[threadIdx.x - off] : 0;
    __syncthreads();
    tmp[threadIdx.x] += u;
    __syncthreads();
  }
  if (i < N) {
    int ex = boff[blockIdx.x] + tmp[threadIdx.x] - v;
    rp[i] = ex;
    cursor[i] = ex;
  }
}

__global__ void init_buckets_kernel(const int* __restrict__ rp, int* __restrict__ bc,
                                    int N, int P) {
  int b = threadIdx.x;
  if (b < P) {
    int lo = b << ABITS;
    if (lo > N) lo = N;
    bc[b] = rp[lo];
  }
}

__global__ __launch_bounds__(1024) void bin_edges_kernel(
    const int* __restrict__ src, const int* __restrict__ dst, int* __restrict__ bc,
    int* __restrict__ arena_src, int* __restrict__ arena_dst, int E) {
  __shared__ int cnt[32], base[32];
  for (long chunk = (long)blockIdx.x * 4096; chunk < E; chunk += (long)gridDim.x * 4096) {
    if (threadIdx.x < 32) cnt[threadIdx.x] = 0;
    __syncthreads();
    int s[4], d[4], b[4], r[4];
#pragma unroll
    for (int u = 0; u < 4; ++u) {
      long e = chunk + threadIdx.x + u * 1024;
      if (e < E) {
        s[u] = src[e];
        d[u] = dst[e];
        b[u] = d[u] >> ABITS;
        r[u] = atomicAdd(&cnt[b[u]], 1);
      }
    }
    __syncthreads();
    if (threadIdx.x < 32) base[threadIdx.x] = cnt[threadIdx.x] ? atomicAdd(&bc[threadIdx.x], cnt[threadIdx.x]) : 0;
    __syncthreads();
#pragma unroll
    for (int u = 0; u < 4; ++u) {
      long e = chunk + threadIdx.x + u * 1024;
      if (e < E) {
        int pos = base[b[u]] + r[u];
        arena_src[pos] = s[u];
        arena_dst[pos] = d[u];
      }
    }
    __syncthreads();
  }
}

__global__ void scatter_bucket_kernel(const int* __restrict__ arena_src,
                                      const int* __restrict__ arena_dst,
                                      const int* __restrict__ rp, int* __restrict__ cursor,
                                      int* __restrict__ col, int lo_node, int hi_node) {
  int start = rp[lo_node], end = rp[hi_node];
  for (int i = start + (int)(blockIdx.x * blockDim.x + threadIdx.x); i < end;
       i += (int)(gridDim.x * blockDim.x)) {
    int s = arena_src[i], d = arena_dst[i];
    int pos = atomicAdd(&cursor[d], 1);
    col[pos] = s;
  }
}

__global__ void graph_bounds_kernel(const int* __restrict__ batch, int* __restrict__ gs,
                                    int N, int G) {
  int n = blockIdx.x * 256 + threadIdx.x;
  if (n >= N) return;
  int b = batch[n];
  int bp = (n == 0) ? -1 : batch[n - 1];
  for (int g = bp + 1; g <= b; ++g) gs[g] = n;
  if (n == N - 1)
    for (int g = b + 1; g <= G; ++g) gs[g] = N;
}

// Prepack W1/W2 into MFMA B-fragment order, split hi/lo bf16.
// Layout: wp[(l*2+g)*8192 + ((nt*2+ks)*2+half)*512 + lane*8 + j]  (ushorts)
// value = W[k=ks*32+(lane>>4)*8+j][n=nt*16+(lane&15)]
__global__ void prepack_w_kernel(const float* __restrict__ W1_rest,
                                 const float* __restrict__ W2, ushort* __restrict__ wp) {
  int l = blockIdx.x >> 1, g = blockIdx.x & 1;
  const float* W;
  if (g == 0) {
    if (l == 0) return;  // layer0 has no 64x64 W1
    W = W1_rest + (size_t)(l - 1) * 4096;
  } else {
    W = W2 + (size_t)l * 4096;
  }
  ushort* out = wp + (size_t)(l * 2 + g) * 8192;
  for (int idx = threadIdx.x; idx < 4096; idx += blockDim.x) {
    int j = idx & 7, lane = (idx >> 3) & 63, ks = (idx >> 9) & 1, nt = (idx >> 10) & 3;
    int k = ks * 32 + (lane >> 4) * 8 + j;
    int n = nt * 16 + (lane & 15);
    float w = W[k * 64 + n];
    ushort hi = f2bf(w);
    ushort lo = f2bf(w - bf2f(hi));
    size_t base = (size_t)((nt * 2 + ks) * 2) * 512 + lane * 8 + j;
    out[base] = hi;
    out[base + 512] = lo;
  }
}

// z[n][:] = (1+eps_l)*h[n][:] + sum_e h[col[e]][:]   (h bf16, z fp32)
__global__ __launch_bounds__(256, 6) void agg_kernel(
    const ushort* __restrict__ hb, const int* __restrict__ rp,
    const int* __restrict__ col, const float* __restrict__ eps,
    int layer, float* __restrict__ z, int N) {
  int lane = threadIdx.x & 63;
  int g = lane >> 3;
  int r = lane & 7;
  int wave = blockIdx.x * (blockDim.x >> 6) + (threadIdx.x >> 6);
  int nwaves = gridDim.x * (blockDim.x >> 6);
  float ep = 1.0f + eps[layer];
  for (int n = wave * 2; n < N; n += nwaves * 2) {
    int n0 = __builtin_amdgcn_readfirstlane(n);
    int n1 = n0 + 1;
    int beg0 = rp[n0];
    int end0 = rp[n0 + 1];
    int end1 = (n1 < N) ? rp[n1 + 1] : end0;
    float a0[8] = {0.f, 0.f, 0.f, 0.f, 0.f, 0.f, 0.f, 0.f};
    float a1[8] = {0.f, 0.f, 0.f, 0.f, 0.f, 0.f, 0.f, 0.f};
    float b0[8] = {0.f, 0.f, 0.f, 0.f, 0.f, 0.f, 0.f, 0.f};
    float b1v[8] = {0.f, 0.f, 0.f, 0.f, 0.f, 0.f, 0.f, 0.f};
    int e0 = beg0 + g;
    int e1 = end0 + g;
    while (e0 < end0 || e1 < end1) {
      if (e0 < end0) {
        int s = col[e0];
        uint4 w = ((const uint4*)(hb + (long)s * 64))[r];
        a0[0] += bf_lo(w.x); a0[1] += bf_hi(w.x);
        a0[2] += bf_lo(w.y); a0[3] += bf_hi(w.y);
        a0[4] += bf_lo(w.z); a0[5] += bf_hi(w.z);
        a0[6] += bf_lo(w.w); a0[7] += bf_hi(w.w);
      }
      if (e0 + 8 < end0) {
        int s = col[e0 + 8];
        uint4 w = ((const uint4*)(hb + (long)s * 64))[r];
        a1[0] += bf_lo(w.x); a1[1] += bf_hi(w.x);
        a1[2] += bf_lo(w.y); a1[3] += bf_hi(w.y);
        a1[4] += bf_lo(w.z); a1[5] += bf_hi(w.z);
        a1[6] += bf_lo(w.w); a1[7] += bf_hi(w.w);
      }
      if (e1 < end1) {
        int s = col[e1];
        uint4 w = ((const uint4*)(hb + (long)s * 64))[r];
        b0[0] += bf_lo(w.x); b0[1] += bf_hi(w.x);
        b0[2] += bf_lo(w.y); b0[3] += bf_hi(w.y);
        b0[4] += bf_lo(w.z); b0[5] += bf_hi(w.z);
        b0[6] += bf_lo(w.w); b0[7] += bf_hi(w.w);
      }
      if (e1 + 8 < end1) {
        int s = col[e1 + 8];
        uint4 w = ((const uint4*)(hb + (long)s * 64))[r];
        b1v[0] += bf_lo(w.x); b1v[1] += bf_hi(w.x);
        b1v[2] += bf_lo(w.y); b1v[3] += bf_hi(w.y);
        b1v[4] += bf_lo(w.z); b1v[5] += bf_hi(w.z);
        b1v[6] += bf_lo(w.w); b1v[7] += bf_hi(w.w);
      }
      e0 += 16; e1 += 16;
    }
#pragma unroll
    for (int j = 0; j < 8; ++j) { a0[j] += a1[j]; b0[j] += b1v[j]; }
#pragma unroll
    for (int m = 8; m <= 32; m <<= 1) {
#pragma unroll
      for (int j = 0; j < 8; ++j) {
        a0[j] += __shfl_xor(a0[j], m, 64);
        b0[j] += __shfl_xor(b0[j], m, 64);
      }
    }
    if (g == 0) {
      uint4 hv = ((const uint4*)(hb + (long)n0 * 64))[r];
      float4 z0, z1;
      z0.x = fmaf(ep, bf_lo(hv.x), a0[0]); z0.y = fmaf(ep, bf_hi(hv.x), a0[1]);
      z0.z = fmaf(ep, bf_lo(hv.y), a0[2]); z0.w = fmaf(ep, bf_hi(hv.y), a0[3]);
      z1.x = fmaf(ep, bf_lo(hv.z), a0[4]); z1.y = fmaf(ep, bf_hi(hv.z), a0[5]);
      z1.z = fmaf(ep, bf_lo(hv.w), a0[6]); z1.w = fmaf(ep, bf_hi(hv.w), a0[7]);
      float4* zr = (float4*)(z + (long)n0 * 64 + r * 8);
      zr[0] = z0; zr[1] = z1;
    } else if (g == 1 && n1 < N) {
      uint4 hv = ((const uint4*)(hb + (long)n1 * 64))[r];
      float4 z0, z1;
      z0.x = fmaf(ep, bf_lo(hv.x), b0[0]); z0.y = fmaf(ep, bf_hi(hv.x), b0[1]);
      z0.z = fmaf(ep, bf_lo(hv.y), b0[2]); z0.w = fmaf(ep, bf_hi(hv.y), b0[3]);
      z1.x = fmaf(ep, bf_lo(hv.z), b0[4]); z1.y = fmaf(ep, bf_hi(hv.z), b0[5]);
      z1.z = fmaf(ep, bf_lo(hv.w), b0[6]); z1.w = fmaf(ep, bf_hi(hv.w), b0[7]);
      float4* zr = (float4*)(z + (long)n1 * 64 + r * 8);
      zr[0] = z0; zr[1] = z1;
    }
  }
}

// ---------------------------------------------------------------------------
// MFMA MLP: block = 64 nodes, 4 waves x 16-node strip. Per wave:
//   A (16x64) from global fp32 rows -> split hi/lo bf16 fragments
//   GEMM1: D[16x64] via 4 N-tiles x 2 K-steps x 3-term mfma_f32_16x16x32_bf16
//   bn1 -> wave-local LDS strip (fp32, pad 68) -> rebuild A frags
//   GEMM2 likewise -> bn2 -> h bf16 stores.
// skip1: input buffer is already t (layer0 path), go straight to GEMM2.
// Layouts (HW-verified per guide): A[m=lane&15][k=quad*8+j],
//   B[k=quad*8+j][n=lane&15], D col=lane&15 row=quad*4+reg.
// ---------------------------------------------------------------------------
__global__ __launch_bounds__(256) void mfma_mlp_kernel(
    const float* __restrict__ zin, ushort* __restrict__ hout,
    const ushort* __restrict__ wp1, const ushort* __restrict__ wp2,
    const float* __restrict__ b1, const float* __restrict__ g1,
    const float* __restrict__ be1, const float* __restrict__ m1,
    const float* __restrict__ v1,
    const float* __restrict__ b2, const float* __restrict__ g2,
    const float* __restrict__ be2, const float* __restrict__ m2,
    const float* __restrict__ v2, int skip1, int N) {
  __shared__ float bnp[6][64];
  __shared__ float tls[4][16][68];
  int tid = threadIdx.x;
  if (tid < 64) {
    bnp[0][tid] = b1[tid];
    float s1 = g1[tid] * rsqrtf(v1[tid] + 1e-5f);
    bnp[1][tid] = s1;
    bnp[2][tid] = be1[tid] - m1[tid] * s1;
    bnp[3][tid] = b2[tid];
    float s2 = g2[tid] * rsqrtf(v2[tid] + 1e-5f);
    bnp[4][tid] = s2;
    bnp[5][tid] = be2[tid] - m2[tid] * s2;
  }
  __syncthreads();
  int wave = tid >> 6, lane = tid & 63;
  int q = lane >> 4, c = lane & 15;
  int base = blockIdx.x * 64 + wave * 16;

  // A fragments from global fp32 rows (z for full mode, t for skip mode)
  short8 ahi0, alo0, ahi1, alo1;
  {
    long row = base + c;
    if (row >= N) row = N - 1;
    const float* zr = zin + row * 64;
    float4 u0 = *(const float4*)(zr + q * 8);
    float4 u1 = *(const float4*)(zr + q * 8 + 4);
    split8(u0, u1, ahi0, alo0);
    u0 = *(const float4*)(zr + 32 + q * 8);
    u1 = *(const float4*)(zr + 32 + q * 8 + 4);
    split8(u0, u1, ahi1, alo1);
  }

  if (!skip1) {
    floatx4 acc[4];
#pragma unroll
    for (int nt = 0; nt < 4; ++nt) acc[nt] = (floatx4){0.f, 0.f, 0.f, 0.f};
#pragma unroll
    for (int nt = 0; nt < 4; ++nt) {
#pragma unroll
      for (int ks = 0; ks < 2; ++ks) {
        const ushort* fb = wp1 + ((nt * 2 + ks) * 2) * 512 + lane * 8;
        short8 bh = *(const short8*)fb;
        short8 bl = *(const short8*)(fb + 512);
        short8 ah = ks ? ahi1 : ahi0;
        short8 al = ks ? alo1 : alo0;
        acc[nt] = __builtin_amdgcn_mfma_f32_16x16x32_bf16(ah, bh, acc[nt], 0, 0, 0);
        acc[nt] = __builtin_amdgcn_mfma_f32_16x16x32_bf16(al, bh, acc[nt], 0, 0, 0);
        acc[nt] = __builtin_amdgcn_mfma_f32_16x16x32_bf16(ah, bl, acc[nt], 0, 0, 0);
      }
    }
    // bn1 -> wave-local LDS strip (no barrier: produced and consumed by this wave)
#pragma unroll
    for (int nt = 0; nt < 4; ++nt) {
      int feat = nt * 16 + c;
      float s1 = bnp[1][feat], o1 = bnp[2][feat], bb = bnp[0][feat];
#pragma unroll
      for (int r = 0; r < 4; ++r) {
        float y = fmaxf(acc[nt][r] + bb, 0.f);
        tls[wave][q * 4 + r][feat] = fmaf(y, s1, o1);
      }
    }
    // rebuild A fragments from LDS t
    float4 u0 = *(const float4*)&tls[wave][c][q * 8];
    float4 u1 = *(const float4*)&tls[wave][c][q * 8 + 4];
    split8(u0, u1, ahi0, alo0);
    u0 = *(const float4*)&tls[wave][c][32 + q * 8];
    u1 = *(const float4*)&tls[wave][c][32 + q * 8 + 4];
    split8(u0, u1, ahi1, alo1);
  }

  // GEMM2
  floatx4 acc2[4];
#pragma unroll
  for (int nt = 0; nt < 4; ++nt) acc2[nt] = (floatx4){0.f, 0.f, 0.f, 0.f};
#pragma unroll
  for (int nt = 0; nt < 4; ++nt) {
#pragma unroll
    for (int ks = 0; ks < 2; ++ks) {
      const ushort* fb = wp2 + ((nt * 2 + ks) * 2) * 512 + lane * 8;
      short8 bh = *(const short8*)fb;
      short8 bl = *(const short8*)(fb + 512);
      short8 ah = ks ? ahi1 : ahi0;
      short8 al = ks ? alo1 : alo0;
      acc2[nt] = __builtin_amdgcn_mfma_f32_16x16x32_bf16(ah, bh, acc2[nt], 0, 0, 0);
      acc2[nt] = __builtin_amdgcn_mfma_f32_16x16x32_bf16(al, bh, acc2[nt], 0, 0, 0);
      acc2[nt] = __builtin_amdgcn_mfma_f32_16x16x32_bf16(ah, bl, acc2[nt], 0, 0, 0);
    }
  }
  // bn2 -> h bf16
#pragma unroll
  for (int nt = 0; nt < 4; ++nt) {
    int feat = nt * 16 + c;
    float s2 = bnp[4][feat], o2 = bnp[5][feat], bb = bnp[3][feat];
#pragma unroll
    for (int r = 0; r < 4; ++r) {
      int node = base + q * 4 + r;
      if (node < N) {
        float y = fmaxf(acc2[nt][r] + bb, 0.f);
        hout[(long)node * 64 + feat] = f2bf(fmaf(y, s2, o2));
      }
    }
  }
}

// layer0 scalar aggregation: z0[n] = (1+eps0)*x[n] + sum x[col[e]]
__global__ void z0_kernel(const float* __restrict__ x, const int* __restrict__ rp,
                          const int* __restrict__ col, const float* __restrict__ eps,
                          float* __restrict__ z0, int N) {
  int n = blockIdx.x * blockDim.x + threadIdx.x;
  if (n >= N) return;
  int beg = rp[n], end = rp[n + 1];
  float a = 0.f;
  for (int e = beg; e < end; ++e) a += x[col[e]];
  z0[n] = fmaf(1.0f + eps[0], x[n], a);
}

// layer0 t: t[n][k] = bn1(relu(z0[n]*W1f[k]+b1[k]))  (fp32 out, feeds GEMM2)
__global__ void t0_kernel(const float* __restrict__ z0, const float* __restrict__ W1f,
                          const float* __restrict__ b1, const float* __restrict__ g1,
                          const float* __restrict__ be1, const float* __restrict__ m1,
                          const float* __restrict__ v1, float* __restrict__ t, int N) {
  int idx = blockIdx.x * blockDim.x + threadIdx.x;
  if (idx >= N * 64) return;
  int n = idx >> 6, k = idx & 63;
  float s = g1[k] * rsqrtf(v1[k] + 1e-5f);
  float y = fmaxf(fmaf(z0[n], W1f[k], b1[k]), 0.f);
  t[idx] = fmaf(y, s, be1[k] - m1[k] * s);
}

__global__ void pool_kernel(const ushort* __restrict__ hb, const int* __restrict__ gs,
                            float* __restrict__ pooled, int layer, int G) {
  int g = blockIdx.x;
  int s = gs[g], e = gs[g + 1];
  int w = threadIdx.x >> 6, lane = threadIdx.x & 63;
  float acc = 0.f;
  for (int n = s + w; n < e; n += 4) {
    ushort u = hb[(long)n * 64 + lane];
    acc += __uint_as_float((uint)u << 16);
  }
  __shared__ float red[4][64];
  red[w][lane] = acc;
  __syncthreads();
  if (w == 0)
    pooled[(long)g * 512 + layer * 64 + lane] =
        ((red[0][lane] + red[1][lane]) + (red[2][lane] + red[3][lane]));
}

__global__ __launch_bounds__(64) void final_kernel(
    const float* __restrict__ pooled, const int* __restrict__ gs,
    const float* __restrict__ lin1_w, const float* __restrict__ lin1_b,
    const float* __restrict__ lin2_w, const float* __restrict__ lin2_b,
    float* __restrict__ out, int G) {
  int g = blockIdx.x;
  int j = threadIdx.x;
  float inv = 1.0f / fmaxf((float)(gs[g + 1] - gs[g]), 1.0f);
  __shared__ float p[512];
  for (int t = j; t < 512; t += 64) p[t] = pooled[(long)g * 512 + t] * inv;
  __syncthreads();
  float a0 = lin1_b[j], a1 = 0.f, a2 = 0.f, a3 = 0.f;
  for (int k = 0; k < 512; k += 4) {
    a0 = fmaf(p[k + 0], lin1_w[(k + 0) * 64 + j], a0);
    a1 = fmaf(p[k + 1], lin1_w[(k + 1) * 64 + j], a1);
    a2 = fmaf(p[k + 2], lin1_w[(k + 2) * 64 + j], a2);
    a3 = fmaf(p[k + 3], lin1_w[(k + 3) * 64 + j], a3);
  }
  float hv = fmaxf((a0 + a1) + (a2 + a3), 0.f);
  __shared__ float hb[64];
  hb[j] = hv;
  __syncthreads();
  __shared__ float lg[3];
  if (j < 3) {
    float a = lin2_b[j];
#pragma unroll
    for (int k = 0; k < 64; ++k) a = fmaf(hb[k], lin2_w[k * 3 + j], a);
    lg[j] = a;
  }
  __syncthreads();
  if (j < 3) {
    float mx = fmaxf(fmaxf(lg[0], lg[1]), lg[2]);
    float lse = mx + logf(expf(lg[0] - mx) + expf(lg[1] - mx) + expf(lg[2] - mx));
    out[g * 3 + j] = lg[j] - lse;
  }
}

extern "C" void kernel_launch(void* const* d_in, const int* in_sizes, int n_in,
                              void* d_out, int out_size, void* d_ws, size_t ws_size,
                              hipStream_t stream) {
  const float* x        = (const float*)d_in[0];
  const int*   edge     = (const int*)d_in[1];
  const int*   batch    = (const int*)d_in[2];
  const float* eps      = (const float*)d_in[4];
  const float* W1_first = (const float*)d_in[5];
  const float* W1_rest  = (const float*)d_in[6];
  const float* b1       = (const float*)d_in[7];
  const float* g1       = (const float*)d_in[8];
  const float* be1      = (const float*)d_in[9];
  const float* m1       = (const float*)d_in[10];
  const float* v1       = (const float*)d_in[11];
  const float* W2       = (const float*)d_in[12];
  const float* b2       = (const float*)d_in[13];
  const float* g2       = (const float*)d_in[14];
  const float* be2      = (const float*)d_in[15];
  const float* m2       = (const float*)d_in[16];
  const float* v2       = (const float*)d_in[17];
  const float* lin1_w   = (const float*)d_in[18];
  const float* lin1_b   = (const float*)d_in[19];
  const float* lin2_w   = (const float*)d_in[20];
  const float* lin2_b   = (const float*)d_in[21];

  int N = in_sizes[0];
  int E = in_sizes[1] / 2;
  int G = out_size / 3;
  const int* esrc = edge;
  const int* edst = edge + E;
  int P = (N + (1 << ABITS) - 1) >> ABITS;
  if (P > 32) P = 32;

  size_t off = 0;
  auto alloc = [&](size_t bytes) -> char* {
    char* p = (char*)d_ws + off;
    off += (bytes + 255) & ~(size_t)255;
    return p;
  };
  int SB = (N + 255) / 256;
  int*    deg    = (int*)alloc((size_t)N * 4);
  int*    rp     = (int*)alloc((size_t)(N + 1) * 4);
  int*    cursor = (int*)alloc((size_t)N * 4);
  int*    col    = (int*)alloc((size_t)E * 4);
  int*    bsum   = (int*)alloc((size_t)SB * 4);
  int*    boff   = (int*)alloc((size_t)SB * 4);
  int*    bc     = (int*)alloc((size_t)32 * 4);
  int*    asrc   = (int*)alloc((size_t)E * 4);
  int*    adst   = (int*)alloc((size_t)E * 4);
  int*    gs     = (int*)alloc((size_t)(G + 1) * 4);
  ushort* wpack  = (ushort*)alloc((size_t)16 * 8192 * 2);
  float*  z0buf  = (float*)alloc((size_t)N * 4);
  float*  zbuf   = (float*)alloc((size_t)N * 64 * 4);
  ushort* hA     = (ushort*)alloc((size_t)N * 64 * 2);
  ushort* hB     = (ushort*)alloc((size_t)N * 64 * 2);
  float*  pooled = (float*)alloc((size_t)G * 512 * 4);
  (void)ws_size;

  hipMemsetAsync(deg, 0, (size_t)N * 4, stream);
  int eb = (E + 255) / 256;
  count_deg_kernel<<<eb, 256, 0, stream>>>(edst, deg, E);
  scan_blocksums<<<SB, 256, 0, stream>>>(deg, bsum, N);
  scan_bsum<<<1, 1024, 0, stream>>>(bsum, boff, rp + N, SB);
  scan_final<<<SB, 256, 0, stream>>>(deg, boff, rp, cursor, N);

  init_buckets_kernel<<<1, 64, 0, stream>>>(rp, bc, N, P);
  int ebA = (E + 4095) / 4096;
  bin_edges_kernel<<<ebA, 1024, 0, stream>>>(esrc, edst, bc, asrc, adst, E);
  for (int b = 0; b < P; ++b) {
    int lo = b << ABITS;
    int hi = (b + 1) << ABITS;
    if (hi > N) hi = N;
    if (lo >= N) break;
    scatter_bucket_kernel<<<1024, 256, 0, stream>>>(asrc, adst, rp, cursor, col, lo, hi);
  }

  graph_bounds_kernel<<<SB, 256, 0, stream>>>(batch, gs, N, G);
  prepack_w_kernel<<<16, 256, 0, stream>>>(W1_rest, W2, wpack);

  int nb = (N + 63) / 64;
  // layer 0
  z0_kernel<<<SB, 256, 0, stream>>>(x, rp, col, eps, z0buf, N);
  t0_kernel<<<(N * 64 + 255) / 256, 256, 0, stream>>>(z0buf, W1_first, b1, g1, be1, m1, v1,
                                                      zbuf, N);
  mfma_mlp_kernel<<<nb, 256, 0, stream>>>(zbuf, hA, wpack, wpack + 8192,
      b1, g1, be1, m1, v1, b2, g2, be2, m2, v2, 1, N);
  pool_kernel<<<G, 256, 0, stream>>>(hA, gs, pooled, 0, G);

  ushort* hin = hA;
  ushort* hout = hB;
  for (int i = 1; i < 8; ++i) {
    agg_kernel<<<2048, 256, 0, stream>>>(hin, rp, col, eps, i, zbuf, N);
    mfma_mlp_kernel<<<nb, 256, 0, stream>>>(zbuf, hout,
        wpack + (size_t)(2 * i) * 8192, wpack + (size_t)(2 * i + 1) * 8192,
        b1 + i * 64, g1 + i * 64, be1 + i * 64, m1 + i * 64, v1 + i * 64,
        b2 + i * 64, g2 + i * 64, be2 + i * 64, m2 + i * 64, v2 + i * 64, 0, N);
    pool_kernel<<<G, 256, 0, stream>>>(hout, gs, pooled, i, G);
    ushort* t = hin; hin = hout; hout = t;
  }
  final_kernel<<<G, 64, 0, stream>>>(pooled, gs, lin1_w, lin1_b,
                                     lin2_w, lin2_b, (float*)d_out, G);
}